// Round 13
// baseline (539.343 us; speedup 1.0000x reference)
//
#include <hip/hip_runtime.h>
#include <cstdint>
#include <cstddef>

#define NN 50000
#define EE 400000
#define BN_EPS 1e-5f
#define NB_SCAN 196   // ceil(50000/256)
#define NWAVE 8192    // 2048 blocks x 4 waves for grid-stride per-node kernels
#define GB 784        // BN stats phase-A blocks (64 rows each)
#define GAGG 2048     // sage_agg blocks (also stats partial count)
#define G2 64         // stage-1 reduce output rows
#define NBIN 64       // degree bins for counting sort
#define NB_SORT 196   // sort blocks of 256 nodes

typedef __attribute__((ext_vector_type(8))) short s16x8;
typedef __attribute__((ext_vector_type(4))) float floatx4;

// bf16 helpers (raw ushort storage, RNE rounding)
__device__ __forceinline__ unsigned short f2b(float f) {
    uint32_t u = __float_as_uint(f);
    uint32_t r = (u + 0x7fffu + ((u >> 16) & 1u)) >> 16;
    return (unsigned short)r;
}
__device__ __forceinline__ uint32_t pack2(float a, float b) {
    return (uint32_t)f2b(a) | ((uint32_t)f2b(b) << 16);
}
__device__ __forceinline__ float b2f_lo(uint32_t u) { return __uint_as_float(u << 16); }
__device__ __forceinline__ float b2f_hi(uint32_t u) { return __uint_as_float(u & 0xffff0000u); }

#define GLD16(g, l) __builtin_amdgcn_global_load_lds(                          \
    (const __attribute__((address_space(1))) uint32_t*)(g),                    \
    (__attribute__((address_space(3))) uint32_t*)(l), 16, 0, 0)

// ---------------------------------------------------------------------------
// Wide bf16 MFMA GEMM (NT): 128 rows x 256 cols per block, 4 waves (2x2 of
// 64x128). Transposed-D epilogue; XOR-swizzled LDS. W has exactly 256 rows.
// Split epilogue fixed at 128: cols 0-127 -> Cb (bf16); 128-255 -> Cf (f32).
// ---------------------------------------------------------------------------
__global__ __launch_bounds__(256)
void gemm_w256(const unsigned short* __restrict__ A,
               const unsigned short* __restrict__ W,
               unsigned short* __restrict__ Cb, float* __restrict__ Cf,
               int M, int K)
{
    __shared__ __align__(16) unsigned short As[128 * 32];   // 8 KB
    __shared__ __align__(16) unsigned short Bs[256 * 32];   // 16 KB
    const int t  = threadIdx.x;
    const int m0 = blockIdx.x * 128;
    const int lane = t & 63;
    const int lr = lane & 15;
    const int lq = lane >> 4;
    const int wid = t >> 6;
    const int wr  = (wid >> 1) * 64;    // wave row base (0 / 64)
    const int wc2 = (wid & 1) * 128;    // wave col base (0 / 128)

    floatx4 acc[4][8];
    const floatx4 zero = {0.f, 0.f, 0.f, 0.f};
    #pragma unroll
    for (int i = 0; i < 4; ++i)
        #pragma unroll
        for (int j = 0; j < 8; ++j) acc[i][j] = zero;

    for (int k0 = 0; k0 < K; k0 += 32) {
        #pragma unroll
        for (int it = 0; it < 2; ++it) {
            const int seg  = t + it * 256;
            const int row  = seg >> 2;
            const int klog = (seg & 3) ^ ((row >> 1) & 3);
            const unsigned short* ga = A + (size_t)min(m0 + row, M - 1) * K + k0 + klog * 8;
            GLD16(ga, As + seg * 8);
        }
        #pragma unroll
        for (int it = 0; it < 4; ++it) {
            const int seg  = t + it * 256;
            const int row  = seg >> 2;
            const int klog = (seg & 3) ^ ((row >> 1) & 3);
            const unsigned short* gb = W + (size_t)row * K + k0 + klog * 8;
            GLD16(gb, Bs + seg * 8);
        }
        __syncthreads();

        s16x8 af[4], bf[8];
        #pragma unroll
        for (int i = 0; i < 4; ++i) {
            const int ra = wr + i * 16 + lr;
            const int pa = lq ^ ((ra >> 1) & 3);
            af[i] = *(const s16x8*)(As + (ra * 4 + pa) * 8);
        }
        #pragma unroll
        for (int j = 0; j < 8; ++j) {
            const int rb = wc2 + j * 16 + lr;
            const int pb = lq ^ ((rb >> 1) & 3);
            bf[j] = *(const s16x8*)(Bs + (rb * 4 + pb) * 8);
        }
        #pragma unroll
        for (int i = 0; i < 4; ++i)
            #pragma unroll
            for (int j = 0; j < 8; ++j)
                acc[i][j] = __builtin_amdgcn_mfma_f32_16x16x32_bf16(
                    bf[j], af[i], acc[i][j], 0, 0, 0);   // transposed D
        __syncthreads();
    }

    const int orow = lane & 15;
    const int oc4  = (lane >> 4) * 4;
    #pragma unroll
    for (int i = 0; i < 4; ++i) {
        const int r = m0 + wr + i * 16 + orow;
        if (r >= M) continue;
        if (wc2 == 0) {
            #pragma unroll
            for (int j = 0; j < 8; ++j) {
                const int c = j * 16 + oc4;
                const floatx4 a = acc[i][j];
                uint2 ov;
                ov.x = pack2(a[0], a[1]);
                ov.y = pack2(a[2], a[3]);
                *(uint2*)(Cb + (size_t)r * 128 + c) = ov;
            }
        } else {
            #pragma unroll
            for (int j = 0; j < 8; ++j) {
                const int c = j * 16 + oc4;
                const floatx4 a = acc[i][j];
                *(float4*)(Cf + (size_t)r * 128 + c) = make_float4(a[0], a[1], a[2], a[3]);
            }
        }
    }
}

// ---------------------------------------------------------------------------
// bf16 MFMA GEMM (NT) 128x128, split epilogue, transposed-D, swizzled LDS.
// Used for layer 4 (Ncol=64, f32 out + bias).
// ---------------------------------------------------------------------------
__global__ __launch_bounds__(256)
void gemm_bf16mm(const unsigned short* __restrict__ A,
                 const unsigned short* __restrict__ W,
                 const float* __restrict__ bias,
                 unsigned short* __restrict__ Cb, float* __restrict__ Cf,
                 int split, int M, int K, int Ncol, int ldb, int ldf)
{
    __shared__ __align__(16) unsigned short As[128 * 32];
    __shared__ __align__(16) unsigned short Bs[128 * 32];
    const int t  = threadIdx.x;
    const int m0 = blockIdx.y * 128;
    const int n0 = blockIdx.x * 128;
    const int lane = t & 63;
    const int lr = lane & 15;
    const int lq = lane >> 4;
    const int wr = (t >> 7) * 64;
    const int wc = ((t >> 6) & 1) * 64;

    floatx4 acc[4][4];
    const floatx4 zero = {0.f, 0.f, 0.f, 0.f};
    #pragma unroll
    for (int i = 0; i < 4; ++i)
        #pragma unroll
        for (int j = 0; j < 4; ++j) acc[i][j] = zero;

    for (int k0 = 0; k0 < K; k0 += 32) {
        #pragma unroll
        for (int it = 0; it < 2; ++it) {
            const int seg  = t + it * 256;
            const int row  = seg >> 2;
            const int klog = (seg & 3) ^ ((row >> 1) & 3);
            const unsigned short* ga = A + (size_t)min(m0 + row, M - 1) * K + k0 + klog * 8;
            GLD16(ga, As + seg * 8);
            const unsigned short* gb = W + (size_t)min(n0 + row, Ncol - 1) * K + k0 + klog * 8;
            GLD16(gb, Bs + seg * 8);
        }
        __syncthreads();

        s16x8 af[4], bf[4];
        #pragma unroll
        for (int i = 0; i < 4; ++i) {
            const int ra = wr + i * 16 + lr;
            const int pa = lq ^ ((ra >> 1) & 3);
            af[i] = *(const s16x8*)(As + (ra * 4 + pa) * 8);
            const int rb = wc + i * 16 + lr;
            const int pb = lq ^ ((rb >> 1) & 3);
            bf[i] = *(const s16x8*)(Bs + (rb * 4 + pb) * 8);
        }
        #pragma unroll
        for (int i = 0; i < 4; ++i)
            #pragma unroll
            for (int j = 0; j < 4; ++j)
                acc[i][j] = __builtin_amdgcn_mfma_f32_16x16x32_bf16(
                    bf[j], af[i], acc[i][j], 0, 0, 0);
        __syncthreads();
    }

    const int orow = lane & 15;
    const int oc4  = (lane >> 4) * 4;
    #pragma unroll
    for (int i = 0; i < 4; ++i) {
        const int r = m0 + wr + i * 16 + orow;
        if (r >= M) continue;
        #pragma unroll
        for (int j = 0; j < 4; ++j) {
            const int cb = n0 + wc + j * 16 + oc4;
            if (cb >= Ncol) continue;
            const floatx4 a = acc[i][j];
            if (cb < split) {
                uint2 ov;
                ov.x = pack2(a[0], a[1]);
                ov.y = pack2(a[2], a[3]);
                *(uint2*)(Cb + (size_t)r * ldb + cb) = ov;
            } else {
                const int cc = cb - split;
                float4 o = make_float4(a[0], a[1], a[2], a[3]);
                if (bias) {
                    o.x += bias[cc]; o.y += bias[cc + 1];
                    o.z += bias[cc + 2]; o.w += bias[cc + 3];
                }
                *(float4*)(Cf + (size_t)r * ldf + cc) = o;
            }
        }
    }
}

// ---------------------------------------------------------------------------
// Per-head GEMM (transposed-D + swizzle, lean epilogue): gat += gbias
// ---------------------------------------------------------------------------
__global__ __launch_bounds__(256)
void gemm_heads(const unsigned short* __restrict__ agg,
                const unsigned short* __restrict__ Wg,
                const float* __restrict__ gbias,
                unsigned short* __restrict__ out)
{
    __shared__ __align__(16) unsigned short As[128 * 32];
    __shared__ __align__(16) unsigned short Bs[128 * 32];
    const int t  = threadIdx.x;
    const int m0 = blockIdx.x * 128;
    const int h  = blockIdx.y;
    const int lane = t & 63;
    const int lr = lane & 15;
    const int lq = lane >> 4;
    const int wr = (t >> 7) * 64;
    const int wc = ((t >> 6) & 1) * 64;

    floatx4 acc[4][4];
    const floatx4 zero = {0.f, 0.f, 0.f, 0.f};
    #pragma unroll
    for (int i = 0; i < 4; ++i)
        #pragma unroll
        for (int j = 0; j < 4; ++j) acc[i][j] = zero;

    for (int k0 = 0; k0 < 128; k0 += 32) {
        #pragma unroll
        for (int it = 0; it < 2; ++it) {
            const int seg  = t + it * 256;
            const int row  = seg >> 2;
            const int klog = (seg & 3) ^ ((row >> 1) & 3);
            const unsigned short* ga = agg + (size_t)min(m0 + row, NN - 1) * 512 + h * 128 + k0 + klog * 8;
            GLD16(ga, As + seg * 8);
            const unsigned short* gb = Wg + (size_t)(h * 128 + row) * 128 + k0 + klog * 8;
            GLD16(gb, Bs + seg * 8);
        }
        __syncthreads();

        s16x8 af[4], bf[4];
        #pragma unroll
        for (int i = 0; i < 4; ++i) {
            const int ra = wr + i * 16 + lr;
            const int pa = lq ^ ((ra >> 1) & 3);
            af[i] = *(const s16x8*)(As + (ra * 4 + pa) * 8);
            const int rb = wc + i * 16 + lr;
            const int pb = lq ^ ((rb >> 1) & 3);
            bf[i] = *(const s16x8*)(Bs + (rb * 4 + pb) * 8);
        }
        #pragma unroll
        for (int i = 0; i < 4; ++i)
            #pragma unroll
            for (int j = 0; j < 4; ++j)
                acc[i][j] = __builtin_amdgcn_mfma_f32_16x16x32_bf16(
                    bf[j], af[i], acc[i][j], 0, 0, 0);
        __syncthreads();
    }

    const int orow = lane & 15;
    const int oc4  = (lane >> 4) * 4;
    #pragma unroll
    for (int i = 0; i < 4; ++i) {
        const int r = m0 + wr + i * 16 + orow;
        if (r >= NN) continue;
        #pragma unroll
        for (int j = 0; j < 4; ++j) {
            const int c = wc + j * 16 + oc4;
            const floatx4 a = acc[i][j];
            const float* gb = gbias + h * 128 + c;
            uint2 ov;
            ov.x = pack2(a[0] + gb[0], a[1] + gb[1]);
            ov.y = pack2(a[2] + gb[2], a[3] + gb[3]);
            *(uint2*)(out + (size_t)r * 512 + h * 128 + c) = ov;
        }
    }
}

// ---------------------------------------------------------------------------
// Merged prep: x->bf16 (blocks 0..6249), weights->bf16 (6250..7305),
// attention projection (7306..7309, h = blockIdx-7306)
// ---------------------------------------------------------------------------
__global__ __launch_bounds__(256)
void k_prep(const float* __restrict__ x, unsigned short* __restrict__ xb,
            const float* __restrict__ s0, const float* __restrict__ s1,
            const float* __restrict__ s2, const float* __restrict__ s3,
            const float* __restrict__ s4, const float* __restrict__ s5,
            unsigned short* __restrict__ wdst,
            const float* __restrict__ a_s, const float* __restrict__ a_d,
            float* __restrict__ ats, float* __restrict__ atd)
{
    const int b = blockIdx.x;
    if (b < 6250) {
        const int i8 = (b * 256 + threadIdx.x) * 8;
        const float4 f0 = *(const float4*)(x + i8);
        const float4 f1 = *(const float4*)(x + i8 + 4);
        uint4 o;
        o.x = pack2(f0.x, f0.y); o.y = pack2(f0.z, f0.w);
        o.z = pack2(f1.x, f1.y); o.w = pack2(f1.z, f1.w);
        *(uint4*)(xb + i8) = o;
    } else if (b < 7306) {
        const int i = (b - 6250) * 256 + threadIdx.x;
        if (i >= 270336) return;
        float v;
        if      (i < 32768)  v = s0[i];
        else if (i < 65536)  v = s1[i - 32768];
        else if (i < 131072) v = s2[i - 65536];
        else if (i < 196608) v = s3[i - 131072];
        else if (i < 262144) v = s4[i - 196608];
        else                 v = s5[i - 262144];
        wdst[i] = f2b(v);
    } else {
        const int h = b - 7306;
        const int k = threadIdx.x;
        if (k >= 128) return;
        float s = 0.f, d = 0.f;
        for (int j = 0; j < 128; ++j) {
            const float w = s2[(size_t)(h * 128 + j) * 128 + k];   // s2 == Wg
            s += a_s[h * 128 + j] * w;
            d += a_d[h * 128 + j] * w;
        }
        ats[h * 128 + k] = s;
        atd[h * 128 + k] = d;
    }
}

// ---------------------------------------------------------------------------
// CSR build: count -> multi-block exclusive scan -> fill
// ---------------------------------------------------------------------------
__global__ void k_count(const int* __restrict__ dst, int* __restrict__ cnt)
{
    int i = blockIdx.x * blockDim.x + threadIdx.x;
    if (i < EE) atomicAdd(&cnt[dst[i]], 1);
}

__global__ __launch_bounds__(256)
void k_scan_blk(const int* __restrict__ cnt, int* __restrict__ offs,
                int* __restrict__ bsum, int N)
{
    __shared__ int wsum[4];
    const int t = threadIdx.x;
    const int i = blockIdx.x * 256 + t;
    const int v = (i < N) ? cnt[i] : 0;
    int s = v;
    #pragma unroll
    for (int o = 1; o < 64; o <<= 1) {
        const int u = __shfl_up(s, o);
        if ((t & 63) >= o) s += u;
    }
    const int wid = t >> 6;
    if ((t & 63) == 63) wsum[wid] = s;
    __syncthreads();
    int base = 0;
    #pragma unroll
    for (int w = 0; w < 3; ++w) if (w < wid) base += wsum[w];
    if (i < N) offs[i] = base + s - v;
    if (t == 255) bsum[blockIdx.x] = base + s;
}

__global__ __launch_bounds__(256)
void k_scan_top(int* __restrict__ bsum, int* __restrict__ offs, int N)
{
    __shared__ int wsum[4];
    const int t = threadIdx.x;
    const int v = (t < NB_SCAN) ? bsum[t] : 0;
    int s = v;
    #pragma unroll
    for (int o = 1; o < 64; o <<= 1) {
        const int u = __shfl_up(s, o);
        if ((t & 63) >= o) s += u;
    }
    const int wid = t >> 6;
    if ((t & 63) == 63) wsum[wid] = s;
    __syncthreads();
    int base = 0;
    #pragma unroll
    for (int w = 0; w < 3; ++w) if (w < wid) base += wsum[w];
    if (t < NB_SCAN) bsum[t] = base + s - v;
    if (t == 255) offs[N] = base + s;
}

__global__ __launch_bounds__(256)
void k_scan_add(int* __restrict__ offs, const int* __restrict__ bsum, int N)
{
    const int i = blockIdx.x * 256 + threadIdx.x;
    if (i < N) offs[i] += bsum[blockIdx.x];
}

__global__ void k_fill(const int* __restrict__ src, const int* __restrict__ dst,
                       const int* __restrict__ offs, int* __restrict__ fill,
                       int* __restrict__ csr)
{
    int i = blockIdx.x * blockDim.x + threadIdx.x;
    if (i < EE) {
        int d = dst[i];
        int p = offs[d] + atomicAdd(&fill[d], 1);
        csr[p] = src[i];
    }
}

// ---------------------------------------------------------------------------
// Degree counting sort (stable, no hot atomics): perm = nodes sorted by deg.
// ---------------------------------------------------------------------------
__global__ __launch_bounds__(256)
void k_lhist(const int* __restrict__ cnt, int* __restrict__ lhist)
{
    __shared__ int h[NBIN];
    const int t = threadIdx.x;
    if (t < NBIN) h[t] = 0;
    __syncthreads();
    const int n = blockIdx.x * 256 + t;
    if (n < NN) atomicAdd(&h[min(cnt[n], NBIN - 1)], 1);
    __syncthreads();
    if (t < NBIN) lhist[blockIdx.x * NBIN + t] = h[t];
}

__global__ __launch_bounds__(64)
void k_hsum(const int* __restrict__ lhist, int* __restrict__ loff,
            int* __restrict__ gbase)
{
    __shared__ int tot[NBIN];
    const int t = threadIdx.x;   // bin
    int run = 0;
    for (int b = 0; b < NB_SORT; ++b) {
        loff[b * NBIN + t] = run;
        run += lhist[b * NBIN + t];
    }
    tot[t] = run;
    __syncthreads();
    if (t == 0) {
        int acc = 0;
        for (int i = 0; i < NBIN; ++i) { const int v = tot[i]; gbase[i] = acc; acc += v; }
    }
}

__global__ __launch_bounds__(256)
void k_perm(const int* __restrict__ cnt, const int* __restrict__ loff,
            const int* __restrict__ gbase, int* __restrict__ perm)
{
    __shared__ unsigned char bins[256];
    const int t = threadIdx.x;
    const int n = blockIdx.x * 256 + t;
    int mybin = 255;
    if (n < NN) {
        mybin = min(cnt[n], NBIN - 1);
        bins[t] = (unsigned char)mybin;
    } else {
        bins[t] = 255;
    }
    __syncthreads();
    if (n < NN) {
        int rank = 0;
        for (int s = 0; s < t; ++s) rank += (bins[s] == (unsigned char)mybin);
        perm[gbase[mybin] + loff[blockIdx.x * NBIN + mybin] + rank] = n;
    }
}

// ---------------------------------------------------------------------------
// SAGE aggregation + fused BN-stats partials: 4 nodes/wave (degree-sorted via
// perm), 8 ch/lane, unroll-2 edge loop.
// ---------------------------------------------------------------------------
__global__ __launch_bounds__(256)
void k_sage_agg(const unsigned short* __restrict__ tl, float* __restrict__ tr,
                const float* __restrict__ bias, const int* __restrict__ offs,
                const int* __restrict__ csr, const int* __restrict__ perm,
                float* __restrict__ P)
{
    __shared__ float red[4][256];
    const int l  = threadIdx.x & 63;
    const int g  = l >> 4;
    const int c0 = (l & 15) * 8;
    const int wid = threadIdx.x >> 6;
    const int wv = blockIdx.x * 4 + wid;
    const float4 bv0 = *(const float4*)(bias + c0);
    const float4 bv1 = *(const float4*)(bias + c0 + 4);
    float ps[8] = {0.f,0.f,0.f,0.f,0.f,0.f,0.f,0.f};
    float qs[8] = {0.f,0.f,0.f,0.f,0.f,0.f,0.f,0.f};
    for (int nb = wv * 4; nb < NN; nb += NWAVE * 4) {
        const int idx = nb + g;
        if (idx < NN) {
            const int n = perm[idx];
            const int o0 = offs[n];
            const int o1 = offs[n + 1];
            const int deg = o1 - o0;
            float a[8] = {0.f,0.f,0.f,0.f,0.f,0.f,0.f,0.f};
            int j = o0;
            for (; j + 1 < o1; j += 2) {
                const int s0 = csr[j];
                const int s1 = csr[j + 1];
                const uint4 q0 = *(const uint4*)(tl + (size_t)s0 * 128 + c0);
                const uint4 q1 = *(const uint4*)(tl + (size_t)s1 * 128 + c0);
                a[0] += b2f_lo(q0.x); a[1] += b2f_hi(q0.x);
                a[2] += b2f_lo(q0.y); a[3] += b2f_hi(q0.y);
                a[4] += b2f_lo(q0.z); a[5] += b2f_hi(q0.z);
                a[6] += b2f_lo(q0.w); a[7] += b2f_hi(q0.w);
                a[0] += b2f_lo(q1.x); a[1] += b2f_hi(q1.x);
                a[2] += b2f_lo(q1.y); a[3] += b2f_hi(q1.y);
                a[4] += b2f_lo(q1.z); a[5] += b2f_hi(q1.z);
                a[6] += b2f_lo(q1.w); a[7] += b2f_hi(q1.w);
            }
            if (j < o1) {
                const int s0 = csr[j];
                const uint4 q0 = *(const uint4*)(tl + (size_t)s0 * 128 + c0);
                a[0] += b2f_lo(q0.x); a[1] += b2f_hi(q0.x);
                a[2] += b2f_lo(q0.y); a[3] += b2f_hi(q0.y);
                a[4] += b2f_lo(q0.z); a[5] += b2f_hi(q0.z);
                a[6] += b2f_lo(q0.w); a[7] += b2f_hi(q0.w);
            }
            const float inv = 1.f / fmaxf((float)deg, 1.f);
            float* tp = tr + (size_t)n * 128 + c0;
            float4 t0 = *(float4*)tp;
            float4 t1 = *(float4*)(tp + 4);
            float v[8];
            v[0] = t0.x + a[0] * inv + bv0.x; v[1] = t0.y + a[1] * inv + bv0.y;
            v[2] = t0.z + a[2] * inv + bv0.z; v[3] = t0.w + a[3] * inv + bv0.w;
            v[4] = t1.x + a[4] * inv + bv1.x; v[5] = t1.y + a[5] * inv + bv1.y;
            v[6] = t1.z + a[6] * inv + bv1.z; v[7] = t1.w + a[7] * inv + bv1.w;
            *(float4*)tp       = make_float4(v[0], v[1], v[2], v[3]);
            *(float4*)(tp + 4) = make_float4(v[4], v[5], v[6], v[7]);
            #pragma unroll
            for (int i = 0; i < 8; ++i) { ps[i] += v[i]; qs[i] += v[i] * v[i]; }
        }
    }
    #pragma unroll
    for (int i = 0; i < 8; ++i) {
        ps[i] += __shfl_xor(ps[i], 16); ps[i] += __shfl_xor(ps[i], 32);
        qs[i] += __shfl_xor(qs[i], 16); qs[i] += __shfl_xor(qs[i], 32);
    }
    if (l < 16) {
        #pragma unroll
        for (int i = 0; i < 8; ++i) {
            red[wid][c0 + i]       = ps[i];
            red[wid][128 + c0 + i] = qs[i];
        }
    }
    __syncthreads();
    const int tc = threadIdx.x;
    const float s = red[0][tc] + red[1][tc] + red[2][tc] + red[3][tc];
    P[(size_t)blockIdx.x * 256 + tc] = s;
}

// ---------------------------------------------------------------------------
// GAT aggregation: 4 nodes/wave (degree-sorted), 8 ch/lane, unroll-2.
// ---------------------------------------------------------------------------
__global__ __launch_bounds__(256)
void k_attn_agg(const unsigned short* __restrict__ h1, const float* __restrict__ asrc,
                const float* __restrict__ adst, const int* __restrict__ offs,
                const int* __restrict__ csr, const int* __restrict__ perm,
                unsigned short* __restrict__ agg)
{
    const int l  = threadIdx.x & 63;
    const int g  = l >> 4;
    const int c0 = (l & 15) * 8;
    const int wv = blockIdx.x * 4 + (threadIdx.x >> 6);
    for (int nb = wv * 4; nb < NN; nb += NWAVE * 4) {
        const int idx = nb + g;
        if (idx >= NN) continue;
        const int n = perm[idx];
        const int o0 = offs[n];
        const int deg = offs[n + 1] - o0;
        const int total = deg + 1;                  // + self loop
        const float4 adv = *(const float4*)(adst + n * 4);
        float den0 = 0.f, den1 = 0.f, den2 = 0.f, den3 = 0.f;
        float acc[4][8];
        #pragma unroll
        for (int h = 0; h < 4; ++h)
            #pragma unroll
            for (int i = 0; i < 8; ++i) acc[h][i] = 0.f;
        int j = 0;
        for (; j + 1 < total; j += 2) {
            const int sidA = (j < deg) ? csr[o0 + j] : n;
            const int sidB = (j + 1 < deg) ? csr[o0 + j + 1] : n;
            const float4 avA = *(const float4*)(asrc + sidA * 4);
            const float4 avB = *(const float4*)(asrc + sidB * 4);
            const uint4 qA = *(const uint4*)(h1 + (size_t)sidA * 128 + c0);
            const uint4 qB = *(const uint4*)(h1 + (size_t)sidB * 128 + c0);
            float eA0 = avA.x + adv.x, eA1 = avA.y + adv.y;
            float eA2 = avA.z + adv.z, eA3 = avA.w + adv.w;
            eA0 = fmaxf(eA0, 0.2f * eA0); eA1 = fmaxf(eA1, 0.2f * eA1);
            eA2 = fmaxf(eA2, 0.2f * eA2); eA3 = fmaxf(eA3, 0.2f * eA3);
            const float wA0 = __expf(eA0), wA1 = __expf(eA1);
            const float wA2 = __expf(eA2), wA3 = __expf(eA3);
            float eB0 = avB.x + adv.x, eB1 = avB.y + adv.y;
            float eB2 = avB.z + adv.z, eB3 = avB.w + adv.w;
            eB0 = fmaxf(eB0, 0.2f * eB0); eB1 = fmaxf(eB1, 0.2f * eB1);
            eB2 = fmaxf(eB2, 0.2f * eB2); eB3 = fmaxf(eB3, 0.2f * eB3);
            const float wB0 = __expf(eB0), wB1 = __expf(eB1);
            const float wB2 = __expf(eB2), wB3 = __expf(eB3);
            den0 += wA0 + wB0; den1 += wA1 + wB1;
            den2 += wA2 + wB2; den3 += wA3 + wB3;
            float vA[8], vB[8];
            vA[0] = b2f_lo(qA.x); vA[1] = b2f_hi(qA.x);
            vA[2] = b2f_lo(qA.y); vA[3] = b2f_hi(qA.y);
            vA[4] = b2f_lo(qA.z); vA[5] = b2f_hi(qA.z);
            vA[6] = b2f_lo(qA.w); vA[7] = b2f_hi(qA.w);
            vB[0] = b2f_lo(qB.x); vB[1] = b2f_hi(qB.x);
            vB[2] = b2f_lo(qB.y); vB[3] = b2f_hi(qB.y);
            vB[4] = b2f_lo(qB.z); vB[5] = b2f_hi(qB.z);
            vB[6] = b2f_lo(qB.w); vB[7] = b2f_hi(qB.w);
            #pragma unroll
            for (int i = 0; i < 8; ++i) {
                acc[0][i] += wA0 * vA[i] + wB0 * vB[i];
                acc[1][i] += wA1 * vA[i] + wB1 * vB[i];
                acc[2][i] += wA2 * vA[i] + wB2 * vB[i];
                acc[3][i] += wA3 * vA[i] + wB3 * vB[i];
            }
        }
        if (j < total) {
            const int sid = (j < deg) ? csr[o0 + j] : n;
            const float4 av = *(const float4*)(asrc + sid * 4);
            const uint4 q = *(const uint4*)(h1 + (size_t)sid * 128 + c0);
            float e0 = av.x + adv.x, e1 = av.y + adv.y;
            float e2 = av.z + adv.z, e3 = av.w + adv.w;
            e0 = fmaxf(e0, 0.2f * e0); e1 = fmaxf(e1, 0.2f * e1);
            e2 = fmaxf(e2, 0.2f * e2); e3 = fmaxf(e3, 0.2f * e3);
            const float w0 = __expf(e0), w1 = __expf(e1);
            const float w2 = __expf(e2), w3 = __expf(e3);
            den0 += w0; den1 += w1; den2 += w2; den3 += w3;
            float v[8];
            v[0] = b2f_lo(q.x); v[1] = b2f_hi(q.x);
            v[2] = b2f_lo(q.y); v[3] = b2f_hi(q.y);
            v[4] = b2f_lo(q.z); v[5] = b2f_hi(q.z);
            v[6] = b2f_lo(q.w); v[7] = b2f_hi(q.w);
            #pragma unroll
            for (int i = 0; i < 8; ++i) {
                acc[0][i] += w0 * v[i];
                acc[1][i] += w1 * v[i];
                acc[2][i] += w2 * v[i];
                acc[3][i] += w3 * v[i];
            }
        }
        const float r[4] = {1.f / den0, 1.f / den1, 1.f / den2, 1.f / den3};
        #pragma unroll
        for (int h = 0; h < 4; ++h) {
            uint4 ov;
            ov.x = pack2(acc[h][0] * r[h], acc[h][1] * r[h]);
            ov.y = pack2(acc[h][2] * r[h], acc[h][3] * r[h]);
            ov.z = pack2(acc[h][4] * r[h], acc[h][5] * r[h]);
            ov.w = pack2(acc[h][6] * r[h], acc[h][7] * r[h]);
            *(uint4*)(agg + (size_t)n * 512 + h * 128 + c0) = ov;
        }
    }
}

// ---------------------------------------------------------------------------
// BN stats phase A: per-block partials, NO atomics.
// ---------------------------------------------------------------------------
__global__ __launch_bounds__(256)
void k_statsA_b2(const unsigned short* __restrict__ X, float* __restrict__ P)
{
    const int c = threadIdx.x * 2;
    const int b = blockIdx.x;
    const int r0 = b * 64;
    const int r1 = min(r0 + 64, NN);
    float s0 = 0.f, s1 = 0.f, q0 = 0.f, q1 = 0.f;
    for (int r = r0; r < r1; ++r) {
        const uint32_t u = *(const uint32_t*)(X + (size_t)r * 512 + c);
        const float v0 = b2f_lo(u), v1 = b2f_hi(u);
        s0 += v0; q0 += v0 * v0;
        s1 += v1; q1 += v1 * v1;
    }
    *(float2*)(P + (size_t)b * 1024 + c) = make_float2(s0, s1);
    *(float2*)(P + (size_t)b * 1024 + 512 + c) = make_float2(q0, q1);
}

__global__ __launch_bounds__(64)
void k_statsA_f(const float* __restrict__ X, float* __restrict__ P)
{
    const int c = threadIdx.x;
    const int b = blockIdx.x;
    const int r0 = b * 64;
    const int r1 = min(r0 + 64, NN);
    float s = 0.f, q = 0.f;
    for (int r = r0; r < r1; ++r) {
        const float v = X[(size_t)r * 64 + c];
        s += v; q += v * v;
    }
    P[(size_t)b * 128 + c] = s;
    P[(size_t)b * 128 + 64 + c] = q;
}

// ---------------------------------------------------------------------------
// Stage-1 tree reduce: P2[g] = sum of rows {g, g+G2, ...} of P (nb x C2).
// ---------------------------------------------------------------------------
__global__ __launch_bounds__(256)
void k_red1(const float* __restrict__ P, float* __restrict__ P2, int C2, int nb)
{
    const int g = blockIdx.x;
    for (int c = threadIdx.x; c < C2; c += 256) {
        float s = 0.f;
        for (int b = g; b < nb; b += G2) s += P[(size_t)b * C2 + c];
        P2[(size_t)g * C2 + c] = s;
    }
}

// ---------------------------------------------------------------------------
// BN stats phase B + final: reduce nb partials, emit scale/shift.
// ---------------------------------------------------------------------------
template<int CHUNK>
__global__ void k_bn_reduce(const float* __restrict__ P, int C, int nb,
                            const float* __restrict__ g, const float* __restrict__ be,
                            float* __restrict__ scale, float* __restrict__ shift)
{
    __shared__ float sb[8 * CHUNK];
    __shared__ float qb[8 * CHUNK];
    const int t = threadIdx.x;
    const int cl = t & (CHUNK - 1);
    const int grp = t / CHUNK;
    const int c = blockIdx.x * CHUNK + cl;
    float s = 0.f, q = 0.f;
    for (int b = grp; b < nb; b += 8) {
        s += P[(size_t)b * 2 * C + c];
        q += P[(size_t)b * 2 * C + C + c];
    }
    sb[grp * CHUNK + cl] = s;
    qb[grp * CHUNK + cl] = q;
    __syncthreads();
    if (t < CHUNK) {
        float S = 0.f, Q = 0.f;
        #pragma unroll
        for (int g2 = 0; g2 < 8; ++g2) { S += sb[g2 * CHUNK + t]; Q += qb[g2 * CHUNK + t]; }
        const int cc = blockIdx.x * CHUNK + t;
        const float mean = S / (float)NN;
        float var = Q / (float)NN - mean * mean;
        var = fmaxf(var, 0.f);
        const float sc = g[cc] * rsqrtf(var + BN_EPS);
        scale[cc] = sc;
        shift[cc] = be[cc] - mean * sc;
    }
}

// ---------------------------------------------------------------------------
__global__ void k_bn_elu_f2b(const float* __restrict__ X, unsigned short* __restrict__ D,
                             const float* __restrict__ scale, const float* __restrict__ shift,
                             int Cm1, int total)
{
    const int i = (blockIdx.x * 256 + threadIdx.x) * 4;
    if (i >= total) return;
    const int c = i & Cm1;
    const float4 x = *(const float4*)(X + i);
    float o[4] = {x.x, x.y, x.z, x.w};
    #pragma unroll
    for (int k = 0; k < 4; ++k) {
        const float v = o[k] * scale[c + k] + shift[c + k];
        o[k] = (v > 0.f) ? v : (__expf(v) - 1.f);
    }
    uint2 ov;
    ov.x = pack2(o[0], o[1]); ov.y = pack2(o[2], o[3]);
    *(uint2*)(D + i) = ov;
}

__global__ void k_bn_elu_b2b(unsigned short* __restrict__ X,
                             const float* __restrict__ scale, const float* __restrict__ shift,
                             int Cm1, int total)
{
    const int i = (blockIdx.x * 256 + threadIdx.x) * 4;
    if (i >= total) return;
    const int c = i & Cm1;
    const uint2 u = *(const uint2*)(X + i);
    float o[4] = {b2f_lo(u.x), b2f_hi(u.x), b2f_lo(u.y), b2f_hi(u.y)};
    #pragma unroll
    for (int k = 0; k < 4; ++k) {
        const float v = o[k] * scale[c + k] + shift[c + k];
        o[k] = (v > 0.f) ? v : (__expf(v) - 1.f);
    }
    uint2 ov;
    ov.x = pack2(o[0], o[1]); ov.y = pack2(o[2], o[3]);
    *(uint2*)(X + i) = ov;
}

// ---------------------------------------------------------------------------
// Fused layer-1 BN+ELU -> h1b (bf16) + GAT coefficients (one wave per node)
// ---------------------------------------------------------------------------
__global__ __launch_bounds__(256)
void k_bn_elu_coef(const float* __restrict__ X, unsigned short* __restrict__ D,
                   const float* __restrict__ scale, const float* __restrict__ shift,
                   const float* __restrict__ ats, const float* __restrict__ atd,
                   float* __restrict__ asrc, float* __restrict__ adst)
{
    const int l = threadIdx.x & 63;
    const int wv = blockIdx.x * 4 + (threadIdx.x >> 6);
    const int c = l * 2;
    const float2 sc = *(const float2*)(scale + c);
    const float2 sh = *(const float2*)(shift + c);
    float2 sa[4], da[4];
    #pragma unroll
    for (int h = 0; h < 4; ++h) {
        sa[h] = *(const float2*)(ats + h * 128 + c);
        da[h] = *(const float2*)(atd + h * 128 + c);
    }
    for (int n = wv; n < NN; n += NWAVE) {
        const float2 xv = *(const float2*)(X + (size_t)n * 128 + c);
        float v0 = xv.x * sc.x + sh.x;
        float v1 = xv.y * sc.y + sh.y;
        v0 = (v0 > 0.f) ? v0 : (__expf(v0) - 1.f);
        v1 = (v1 > 0.f) ? v1 : (__expf(v1) - 1.f);
        const uint32_t p = pack2(v0, v1);
        *(uint32_t*)(D + (size_t)n * 128 + c) = p;
        const float r0 = b2f_lo(p), r1 = b2f_hi(p);   // use bf16-rounded values
        float ps[4], pd[4];
        #pragma unroll
        for (int h = 0; h < 4; ++h) {
            ps[h] = r0 * sa[h].x + r1 * sa[h].y;
            pd[h] = r0 * da[h].x + r1 * da[h].y;
        }
        #pragma unroll
        for (int o = 1; o < 64; o <<= 1) {
            #pragma unroll
            for (int h = 0; h < 4; ++h) {
                ps[h] += __shfl_xor(ps[h], o);
                pd[h] += __shfl_xor(pd[h], o);
            }
        }
        if (l == 0) {
            *(float4*)(asrc + n * 4) = make_float4(ps[0], ps[1], ps[2], ps[3]);
            *(float4*)(adst + n * 4) = make_float4(pd[0], pd[1], pd[2], pd[3]);
        }
    }
}

// ---------------------------------------------------------------------------
// Fused layer-4 BN+ELU + final linear (grid-stride, one wave per node)
// ---------------------------------------------------------------------------
__global__ __launch_bounds__(256)
void k_bn_elu_fc2(const float* __restrict__ X, const float* __restrict__ scale,
                  const float* __restrict__ shift, const float* __restrict__ W,
                  const float* __restrict__ bias, float* __restrict__ out)
{
    const int c = threadIdx.x & 63;
    const int gw = blockIdx.x * 4 + (threadIdx.x >> 6);
    const float sc = scale[c], sh = shift[c];
    const float w0 = W[c], w1 = W[64 + c];
    const float b0 = bias[0], b1 = bias[1];
    for (int n = gw; n < NN; n += NWAVE) {
        float v = X[(size_t)n * 64 + c] * sc + sh;
        v = (v > 0.f) ? v : (__expf(v) - 1.f);
        float p0 = v * w0;
        float p1 = v * w1;
        #pragma unroll
        for (int o = 1; o < 64; o <<= 1) {
            p0 += __shfl_xor(p0, o);
            p1 += __shfl_xor(p1, o);
        }
        if (c == 0) {
            out[n * 2 + 0] = p0 + b0;
            out[n * 2 + 1] = p1 + b1;
        }
    }
}

// ---------------------------------------------------------------------------
extern "C" void kernel_launch(void* const* d_in, const int* in_sizes, int n_in,
                              void* d_out, int out_size, void* d_ws, size_t ws_size,
                              hipStream_t stream)
{
    const float* x     = (const float*)d_in[0];
    const int*   ei    = (const int*)d_in[1];
    const float* W1l   = (const float*)d_in[2];
    const float* b1    = (const float*)d_in[3];
    const float* W1r   = (const float*)d_in[4];
    const float* g1    = (const float*)d_in[5];
    const float* be1   = (const float*)d_in[6];
    const float* Wg    = (const float*)d_in[7];
    const float* a_s   = (const float*)d_in[8];
    const float* a_d   = (const float*)d_in[9];
    const float* gbias = (const float*)d_in[10];
    const float* g2    = (const float*)d_in[11];
    const float* be2   = (const float*)d_in[12];
    const float* W2l   = (const float*)d_in[13];
    const float* b2    = (const float*)d_in[14];
    const float* W2r   = (const float*)d_in[15];
    const float* g3    = (const float*)d_in[16];
    const float* be3   = (const float*)d_in[17];
    const float* Wf1   = (const float*)d_in[18];
    const float* bf1   = (const float*)d_in[19];
    const float* g4    = (const float*)d_in[20];
    const float* be4   = (const float*)d_in[21];
    const float* Wf2   = (const float*)d_in[22];
    const float* bf2   = (const float*)d_in[23];
    const int* src = ei;
    const int* dst = ei + EE;

    char* ws = (char*)d_ws;
    size_t off = 0;
    auto alloc = [&](size_t bytes) -> char* {
        char* p = ws + off;
        off += (bytes + 255) & ~(size_t)255;
        return p;
    };
    unsigned short* xb   = (unsigned short*)alloc((size_t)NN * 256 * 2);
    unsigned short* waren= (unsigned short*)alloc(270336 * 2);
    unsigned short* tlb  = (unsigned short*)alloc((size_t)NN * 128 * 2);
    float*          trF  = (float*)alloc((size_t)NN * 128 * 4);
    unsigned short* h1b  = (unsigned short*)alloc((size_t)NN * 128 * 2);
    unsigned short* aggb = (unsigned short*)alloc((size_t)NN * 512 * 2);
    unsigned short* gatb = (unsigned short*)alloc((size_t)NN * 512 * 2);
    float* asrc  = (float*)alloc((size_t)NN * 4 * 4);
    float* adst  = (float*)alloc((size_t)NN * 4 * 4);
    float* ats   = (float*)alloc(512 * 4);
    float* atd   = (float*)alloc(512 * 4);
    float* pstat = (float*)alloc((size_t)GB * 1024 * 4);    // 3.2 MB (max user)
    float* pstat2= (float*)alloc((size_t)G2 * 1024 * 4);    // 256 KB stage-1 out
    float* scsh  = (float*)alloc(1024 * 4);
    int*   cntfill = (int*)alloc((size_t)NN * 2 * 4);
    int*   offs  = (int*)alloc((size_t)(NN + 1) * 4);
    int*   csr   = (int*)alloc((size_t)EE * 4);
    int*   bsum  = (int*)alloc((size_t)NB_SCAN * 4);
    int*   lhist = (int*)alloc((size_t)NB_SORT * NBIN * 4);
    int*   loff  = (int*)alloc((size_t)NB_SORT * NBIN * 4);
    int*   gbase = (int*)alloc((size_t)NBIN * 4);
    int*   perm  = (int*)alloc((size_t)NN * 4);
    if (off > ws_size) return;
    (void)in_sizes; (void)n_in; (void)out_size;

    unsigned short* W1cat = waren;            // W1l || W1r : 256 rows x 256
    unsigned short* Wg_b  = waren + 65536;    // 512 x 128
    unsigned short* W2cat = waren + 131072;   // W2l || W2r : 256 rows x 512
    unsigned short* Wf1_b = waren + 262144;   // 64 x 128

    int* cnt  = cntfill;
    int* fill = cntfill + NN;
    float* scale = scsh;
    float* shift = scsh + 512;

    // ---- prep (converts + attention projection) + CSR build + degree sort ----
    k_prep<<<7310, 256, 0, stream>>>(x, xb, W1l, W1r, Wg, W2l, W2r, Wf1, waren,
                                     a_s, a_d, ats, atd);
    hipMemsetAsync(cntfill, 0, (size_t)NN * 2 * 4, stream);
    k_count<<<(EE + 255) / 256, 256, 0, stream>>>(dst, cnt);
    k_scan_blk<<<NB_SCAN, 256, 0, stream>>>(cnt, offs, bsum, NN);
    k_scan_top<<<1, 256, 0, stream>>>(bsum, offs, NN);
    k_scan_add<<<NB_SCAN, 256, 0, stream>>>(offs, bsum, NN);
    k_fill<<<(EE + 255) / 256, 256, 0, stream>>>(src, dst, offs, fill, csr);
    k_lhist<<<NB_SORT, 256, 0, stream>>>(cnt, lhist);
    k_hsum<<<1, 64, 0, stream>>>(lhist, loff, gbase);
    k_perm<<<NB_SORT, 256, 0, stream>>>(cnt, loff, gbase, perm);

    const int gy = (NN + 127) / 128;   // 391

    // ---- Layer 1: SAGE(256 -> 128) + BN + ELU (+coef fused) ----
    gemm_w256<<<gy, 256, 0, stream>>>(xb, W1cat, tlb, trF, NN, 256);
    k_sage_agg<<<GAGG, 256, 0, stream>>>(tlb, trF, b1, offs, csr, perm, pstat);
    k_red1<<<G2, 256, 0, stream>>>(pstat, pstat2, 256, GAGG);
    k_bn_reduce<128><<<1, 1024, 0, stream>>>(pstat2, 128, G2, g1, be1, scale, shift);
    k_bn_elu_coef<<<2048, 256, 0, stream>>>(trF, h1b, scale, shift, ats, atd, asrc, adst);

    // ---- Layer 2: GAT(128 -> 4x128) + BN + ELU ----
    k_attn_agg<<<2048, 256, 0, stream>>>(h1b, asrc, adst, offs, csr, perm, aggb);
    gemm_heads<<<dim3(gy, 4), 256, 0, stream>>>(aggb, Wg_b, gbias, gatb);
    k_statsA_b2<<<GB, 256, 0, stream>>>(gatb, pstat);
    k_red1<<<G2, 256, 0, stream>>>(pstat, pstat2, 1024, GB);
    k_bn_reduce<128><<<4, 1024, 0, stream>>>(pstat2, 512, G2, g2, be2, scale, shift);
    k_bn_elu_b2b<<<(NN * 512 / 4 + 255) / 256, 256, 0, stream>>>(gatb, scale, shift, 511, NN * 512);

    // ---- Layer 3: SAGE(512 -> 128) + BN + ELU ----
    gemm_w256<<<gy, 256, 0, stream>>>(gatb, W2cat, tlb, trF, NN, 512);
    k_sage_agg<<<GAGG, 256, 0, stream>>>(tlb, trF, b2, offs, csr, perm, pstat);
    k_red1<<<G2, 256, 0, stream>>>(pstat, pstat2, 256, GAGG);
    k_bn_reduce<128><<<1, 1024, 0, stream>>>(pstat2, 128, G2, g3, be3, scale, shift);
    k_bn_elu_f2b<<<(NN * 128 / 4 + 255) / 256, 256, 0, stream>>>(trF, h1b, scale, shift, 127, NN * 128);

    // ---- Layer 4: Linear(128 -> 64) + BN ----
    gemm_bf16mm<<<dim3(1, gy), 256, 0, stream>>>(h1b, Wf1_b, bf1, nullptr, trF,
                                                 0, NN, 128, 64, 0, 64);
    k_statsA_f<<<GB, 64, 0, stream>>>(trF, pstat);
    k_red1<<<G2, 256, 0, stream>>>(pstat, pstat2, 128, GB);
    k_bn_reduce<64><<<1, 512, 0, stream>>>(pstat2, 64, G2, g4, be4, scale, shift);

    // ---- Layer 4 ELU + Layer 5 Linear(64 -> 2), fused ----
    k_bn_elu_fc2<<<2048, 256, 0, stream>>>(trF, scale, shift, Wf2, bf2, (float*)d_out);
}

// Round 14
// 526.378 us; speedup vs baseline: 1.0246x; 1.0246x over previous
//
#include <hip/hip_runtime.h>
#include <cstdint>
#include <cstddef>

#define NN 50000
#define EE 400000
#define BN_EPS 1e-5f
#define NB_SCAN 196   // ceil(50000/256)
#define NWAVE 8192    // 2048 blocks x 4 waves for grid-stride per-node kernels
#define GB 784        // BN stats phase-A blocks (64 rows each)
#define GAGG 2048     // sage_agg blocks (also stats partial count)
#define G2 64         // stage-1 reduce output rows

typedef __attribute__((ext_vector_type(8))) short s16x8;
typedef __attribute__((ext_vector_type(4))) float floatx4;

// bf16 helpers (raw ushort storage, RNE rounding)
__device__ __forceinline__ unsigned short f2b(float f) {
    uint32_t u = __float_as_uint(f);
    uint32_t r = (u + 0x7fffu + ((u >> 16) & 1u)) >> 16;
    return (unsigned short)r;
}
__device__ __forceinline__ uint32_t pack2(float a, float b) {
    return (uint32_t)f2b(a) | ((uint32_t)f2b(b) << 16);
}
__device__ __forceinline__ float b2f_lo(uint32_t u) { return __uint_as_float(u << 16); }
__device__ __forceinline__ float b2f_hi(uint32_t u) { return __uint_as_float(u & 0xffff0000u); }

#define GLD16(g, l) __builtin_amdgcn_global_load_lds(                          \
    (const __attribute__((address_space(1))) uint32_t*)(g),                    \
    (__attribute__((address_space(3))) uint32_t*)(l), 16, 0, 0)

// ---------------------------------------------------------------------------
// Wide bf16 MFMA GEMM (NT): 128 rows x 256 cols per block, 4 waves (2x2 of
// 64x128). Transposed-D epilogue; XOR-swizzled LDS. W has exactly 256 rows.
// Split epilogue fixed at 128: cols 0-127 -> Cb (bf16); 128-255 -> Cf (f32).
// ---------------------------------------------------------------------------
__global__ __launch_bounds__(256)
void gemm_w256(const unsigned short* __restrict__ A,
               const unsigned short* __restrict__ W,
               unsigned short* __restrict__ Cb, float* __restrict__ Cf,
               int M, int K)
{
    __shared__ __align__(16) unsigned short As[128 * 32];   // 8 KB
    __shared__ __align__(16) unsigned short Bs[256 * 32];   // 16 KB
    const int t  = threadIdx.x;
    const int m0 = blockIdx.x * 128;
    const int lane = t & 63;
    const int lr = lane & 15;
    const int lq = lane >> 4;
    const int wid = t >> 6;
    const int wr  = (wid >> 1) * 64;    // wave row base (0 / 64)
    const int wc2 = (wid & 1) * 128;    // wave col base (0 / 128)

    floatx4 acc[4][8];
    const floatx4 zero = {0.f, 0.f, 0.f, 0.f};
    #pragma unroll
    for (int i = 0; i < 4; ++i)
        #pragma unroll
        for (int j = 0; j < 8; ++j) acc[i][j] = zero;

    for (int k0 = 0; k0 < K; k0 += 32) {
        #pragma unroll
        for (int it = 0; it < 2; ++it) {
            const int seg  = t + it * 256;
            const int row  = seg >> 2;
            const int klog = (seg & 3) ^ ((row >> 1) & 3);
            const unsigned short* ga = A + (size_t)min(m0 + row, M - 1) * K + k0 + klog * 8;
            GLD16(ga, As + seg * 8);
        }
        #pragma unroll
        for (int it = 0; it < 4; ++it) {
            const int seg  = t + it * 256;
            const int row  = seg >> 2;
            const int klog = (seg & 3) ^ ((row >> 1) & 3);
            const unsigned short* gb = W + (size_t)row * K + k0 + klog * 8;
            GLD16(gb, Bs + seg * 8);
        }
        __syncthreads();

        s16x8 af[4], bf[8];
        #pragma unroll
        for (int i = 0; i < 4; ++i) {
            const int ra = wr + i * 16 + lr;
            const int pa = lq ^ ((ra >> 1) & 3);
            af[i] = *(const s16x8*)(As + (ra * 4 + pa) * 8);
        }
        #pragma unroll
        for (int j = 0; j < 8; ++j) {
            const int rb = wc2 + j * 16 + lr;
            const int pb = lq ^ ((rb >> 1) & 3);
            bf[j] = *(const s16x8*)(Bs + (rb * 4 + pb) * 8);
        }
        #pragma unroll
        for (int i = 0; i < 4; ++i)
            #pragma unroll
            for (int j = 0; j < 8; ++j)
                acc[i][j] = __builtin_amdgcn_mfma_f32_16x16x32_bf16(
                    bf[j], af[i], acc[i][j], 0, 0, 0);   // transposed D
        __syncthreads();
    }

    const int orow = lane & 15;
    const int oc4  = (lane >> 4) * 4;
    #pragma unroll
    for (int i = 0; i < 4; ++i) {
        const int r = m0 + wr + i * 16 + orow;
        if (r >= M) continue;
        if (wc2 == 0) {
            #pragma unroll
            for (int j = 0; j < 8; ++j) {
                const int c = j * 16 + oc4;
                const floatx4 a = acc[i][j];
                uint2 ov;
                ov.x = pack2(a[0], a[1]);
                ov.y = pack2(a[2], a[3]);
                *(uint2*)(Cb + (size_t)r * 128 + c) = ov;
            }
        } else {
            #pragma unroll
            for (int j = 0; j < 8; ++j) {
                const int c = j * 16 + oc4;
                const floatx4 a = acc[i][j];
                *(float4*)(Cf + (size_t)r * 128 + c) = make_float4(a[0], a[1], a[2], a[3]);
            }
        }
    }
}

// ---------------------------------------------------------------------------
// bf16 MFMA GEMM (NT) 128x128, split epilogue, transposed-D, swizzled LDS.
// Used for layer 4 (Ncol=64, f32 out + bias).
// ---------------------------------------------------------------------------
__global__ __launch_bounds__(256)
void gemm_bf16mm(const unsigned short* __restrict__ A,
                 const unsigned short* __restrict__ W,
                 const float* __restrict__ bias,
                 unsigned short* __restrict__ Cb, float* __restrict__ Cf,
                 int split, int M, int K, int Ncol, int ldb, int ldf)
{
    __shared__ __align__(16) unsigned short As[128 * 32];
    __shared__ __align__(16) unsigned short Bs[128 * 32];
    const int t  = threadIdx.x;
    const int m0 = blockIdx.y * 128;
    const int n0 = blockIdx.x * 128;
    const int lane = t & 63;
    const int lr = lane & 15;
    const int lq = lane >> 4;
    const int wr = (t >> 7) * 64;
    const int wc = ((t >> 6) & 1) * 64;

    floatx4 acc[4][4];
    const floatx4 zero = {0.f, 0.f, 0.f, 0.f};
    #pragma unroll
    for (int i = 0; i < 4; ++i)
        #pragma unroll
        for (int j = 0; j < 4; ++j) acc[i][j] = zero;

    for (int k0 = 0; k0 < K; k0 += 32) {
        #pragma unroll
        for (int it = 0; it < 2; ++it) {
            const int seg  = t + it * 256;
            const int row  = seg >> 2;
            const int klog = (seg & 3) ^ ((row >> 1) & 3);
            const unsigned short* ga = A + (size_t)min(m0 + row, M - 1) * K + k0 + klog * 8;
            GLD16(ga, As + seg * 8);
            const unsigned short* gb = W + (size_t)min(n0 + row, Ncol - 1) * K + k0 + klog * 8;
            GLD16(gb, Bs + seg * 8);
        }
        __syncthreads();

        s16x8 af[4], bf[4];
        #pragma unroll
        for (int i = 0; i < 4; ++i) {
            const int ra = wr + i * 16 + lr;
            const int pa = lq ^ ((ra >> 1) & 3);
            af[i] = *(const s16x8*)(As + (ra * 4 + pa) * 8);
            const int rb = wc + i * 16 + lr;
            const int pb = lq ^ ((rb >> 1) & 3);
            bf[i] = *(const s16x8*)(Bs + (rb * 4 + pb) * 8);
        }
        #pragma unroll
        for (int i = 0; i < 4; ++i)
            #pragma unroll
            for (int j = 0; j < 4; ++j)
                acc[i][j] = __builtin_amdgcn_mfma_f32_16x16x32_bf16(
                    bf[j], af[i], acc[i][j], 0, 0, 0);
        __syncthreads();
    }

    const int orow = lane & 15;
    const int oc4  = (lane >> 4) * 4;
    #pragma unroll
    for (int i = 0; i < 4; ++i) {
        const int r = m0 + wr + i * 16 + orow;
        if (r >= M) continue;
        #pragma unroll
        for (int j = 0; j < 4; ++j) {
            const int cb = n0 + wc + j * 16 + oc4;
            if (cb >= Ncol) continue;
            const floatx4 a = acc[i][j];
            if (cb < split) {
                uint2 ov;
                ov.x = pack2(a[0], a[1]);
                ov.y = pack2(a[2], a[3]);
                *(uint2*)(Cb + (size_t)r * ldb + cb) = ov;
            } else {
                const int cc = cb - split;
                float4 o = make_float4(a[0], a[1], a[2], a[3]);
                if (bias) {
                    o.x += bias[cc]; o.y += bias[cc + 1];
                    o.z += bias[cc + 2]; o.w += bias[cc + 3];
                }
                *(float4*)(Cf + (size_t)r * ldf + cc) = o;
            }
        }
    }
}

// ---------------------------------------------------------------------------
// Per-head GEMM (transposed-D + swizzle, lean epilogue): gat += gbias
// ---------------------------------------------------------------------------
__global__ __launch_bounds__(256)
void gemm_heads(const unsigned short* __restrict__ agg,
                const unsigned short* __restrict__ Wg,
                const float* __restrict__ gbias,
                unsigned short* __restrict__ out)
{
    __shared__ __align__(16) unsigned short As[128 * 32];
    __shared__ __align__(16) unsigned short Bs[128 * 32];
    const int t  = threadIdx.x;
    const int m0 = blockIdx.x * 128;
    const int h  = blockIdx.y;
    const int lane = t & 63;
    const int lr = lane & 15;
    const int lq = lane >> 4;
    const int wr = (t >> 7) * 64;
    const int wc = ((t >> 6) & 1) * 64;

    floatx4 acc[4][4];
    const floatx4 zero = {0.f, 0.f, 0.f, 0.f};
    #pragma unroll
    for (int i = 0; i < 4; ++i)
        #pragma unroll
        for (int j = 0; j < 4; ++j) acc[i][j] = zero;

    for (int k0 = 0; k0 < 128; k0 += 32) {
        #pragma unroll
        for (int it = 0; it < 2; ++it) {
            const int seg  = t + it * 256;
            const int row  = seg >> 2;
            const int klog = (seg & 3) ^ ((row >> 1) & 3);
            const unsigned short* ga = agg + (size_t)min(m0 + row, NN - 1) * 512 + h * 128 + k0 + klog * 8;
            GLD16(ga, As + seg * 8);
            const unsigned short* gb = Wg + (size_t)(h * 128 + row) * 128 + k0 + klog * 8;
            GLD16(gb, Bs + seg * 8);
        }
        __syncthreads();

        s16x8 af[4], bf[4];
        #pragma unroll
        for (int i = 0; i < 4; ++i) {
            const int ra = wr + i * 16 + lr;
            const int pa = lq ^ ((ra >> 1) & 3);
            af[i] = *(const s16x8*)(As + (ra * 4 + pa) * 8);
            const int rb = wc + i * 16 + lr;
            const int pb = lq ^ ((rb >> 1) & 3);
            bf[i] = *(const s16x8*)(Bs + (rb * 4 + pb) * 8);
        }
        #pragma unroll
        for (int i = 0; i < 4; ++i)
            #pragma unroll
            for (int j = 0; j < 4; ++j)
                acc[i][j] = __builtin_amdgcn_mfma_f32_16x16x32_bf16(
                    bf[j], af[i], acc[i][j], 0, 0, 0);
        __syncthreads();
    }

    const int orow = lane & 15;
    const int oc4  = (lane >> 4) * 4;
    #pragma unroll
    for (int i = 0; i < 4; ++i) {
        const int r = m0 + wr + i * 16 + orow;
        if (r >= NN) continue;
        #pragma unroll
        for (int j = 0; j < 4; ++j) {
            const int c = wc + j * 16 + oc4;
            const floatx4 a = acc[i][j];
            const float* gb = gbias + h * 128 + c;
            uint2 ov;
            ov.x = pack2(a[0] + gb[0], a[1] + gb[1]);
            ov.y = pack2(a[2] + gb[2], a[3] + gb[3]);
            *(uint2*)(out + (size_t)r * 512 + h * 128 + c) = ov;
        }
    }
}

// ---------------------------------------------------------------------------
// Merged prep: x->bf16 (blocks 0..6249), weights->bf16 (6250..7305),
// attention projection (7306..7309, h = blockIdx-7306)
// ---------------------------------------------------------------------------
__global__ __launch_bounds__(256)
void k_prep(const float* __restrict__ x, unsigned short* __restrict__ xb,
            const float* __restrict__ s0, const float* __restrict__ s1,
            const float* __restrict__ s2, const float* __restrict__ s3,
            const float* __restrict__ s4, const float* __restrict__ s5,
            unsigned short* __restrict__ wdst,
            const float* __restrict__ a_s, const float* __restrict__ a_d,
            float* __restrict__ ats, float* __restrict__ atd)
{
    const int b = blockIdx.x;
    if (b < 6250) {
        const int i8 = (b * 256 + threadIdx.x) * 8;
        const float4 f0 = *(const float4*)(x + i8);
        const float4 f1 = *(const float4*)(x + i8 + 4);
        uint4 o;
        o.x = pack2(f0.x, f0.y); o.y = pack2(f0.z, f0.w);
        o.z = pack2(f1.x, f1.y); o.w = pack2(f1.z, f1.w);
        *(uint4*)(xb + i8) = o;
    } else if (b < 7306) {
        const int i = (b - 6250) * 256 + threadIdx.x;
        if (i >= 270336) return;
        float v;
        if      (i < 32768)  v = s0[i];
        else if (i < 65536)  v = s1[i - 32768];
        else if (i < 131072) v = s2[i - 65536];
        else if (i < 196608) v = s3[i - 131072];
        else if (i < 262144) v = s4[i - 196608];
        else                 v = s5[i - 262144];
        wdst[i] = f2b(v);
    } else {
        const int h = b - 7306;
        const int k = threadIdx.x;
        if (k >= 128) return;
        float s = 0.f, d = 0.f;
        for (int j = 0; j < 128; ++j) {
            const float w = s2[(size_t)(h * 128 + j) * 128 + k];   // s2 == Wg
            s += a_s[h * 128 + j] * w;
            d += a_d[h * 128 + j] * w;
        }
        ats[h * 128 + k] = s;
        atd[h * 128 + k] = d;
    }
}

// ---------------------------------------------------------------------------
// CSR build: count -> multi-block exclusive scan -> fill
// ---------------------------------------------------------------------------
__global__ void k_count(const int* __restrict__ dst, int* __restrict__ cnt)
{
    int i = blockIdx.x * blockDim.x + threadIdx.x;
    if (i < EE) atomicAdd(&cnt[dst[i]], 1);
}

__global__ __launch_bounds__(256)
void k_scan_blk(const int* __restrict__ cnt, int* __restrict__ offs,
                int* __restrict__ bsum, int N)
{
    __shared__ int wsum[4];
    const int t = threadIdx.x;
    const int i = blockIdx.x * 256 + t;
    const int v = (i < N) ? cnt[i] : 0;
    int s = v;
    #pragma unroll
    for (int o = 1; o < 64; o <<= 1) {
        const int u = __shfl_up(s, o);
        if ((t & 63) >= o) s += u;
    }
    const int wid = t >> 6;
    if ((t & 63) == 63) wsum[wid] = s;
    __syncthreads();
    int base = 0;
    #pragma unroll
    for (int w = 0; w < 3; ++w) if (w < wid) base += wsum[w];
    if (i < N) offs[i] = base + s - v;
    if (t == 255) bsum[blockIdx.x] = base + s;
}

__global__ __launch_bounds__(256)
void k_scan_top(int* __restrict__ bsum, int* __restrict__ offs, int N)
{
    __shared__ int wsum[4];
    const int t = threadIdx.x;
    const int v = (t < NB_SCAN) ? bsum[t] : 0;
    int s = v;
    #pragma unroll
    for (int o = 1; o < 64; o <<= 1) {
        const int u = __shfl_up(s, o);
        if ((t & 63) >= o) s += u;
    }
    const int wid = t >> 6;
    if ((t & 63) == 63) wsum[wid] = s;
    __syncthreads();
    int base = 0;
    #pragma unroll
    for (int w = 0; w < 3; ++w) if (w < wid) base += wsum[w];
    if (t < NB_SCAN) bsum[t] = base + s - v;
    if (t == 255) offs[N] = base + s;
}

__global__ __launch_bounds__(256)
void k_scan_add(int* __restrict__ offs, const int* __restrict__ bsum, int N)
{
    const int i = blockIdx.x * 256 + threadIdx.x;
    if (i < N) offs[i] += bsum[blockIdx.x];
}

__global__ void k_fill(const int* __restrict__ src, const int* __restrict__ dst,
                       const int* __restrict__ offs, int* __restrict__ fill,
                       int* __restrict__ csr)
{
    int i = blockIdx.x * blockDim.x + threadIdx.x;
    if (i < EE) {
        int d = dst[i];
        int p = offs[d] + atomicAdd(&fill[d], 1);
        csr[p] = src[i];
    }
}

// ---------------------------------------------------------------------------
// SAGE aggregation + fused BN-stats partials: 4 nodes/wave, 8 ch/lane,
// unroll-2 edge loop (two independent load chains in flight).
// ---------------------------------------------------------------------------
__global__ __launch_bounds__(256)
void k_sage_agg(const unsigned short* __restrict__ tl, float* __restrict__ tr,
                const float* __restrict__ bias, const int* __restrict__ offs,
                const int* __restrict__ csr, float* __restrict__ P)
{
    __shared__ float red[4][256];
    const int l  = threadIdx.x & 63;
    const int g  = l >> 4;
    const int c0 = (l & 15) * 8;
    const int wid = threadIdx.x >> 6;
    const int wv = blockIdx.x * 4 + wid;
    const float4 bv0 = *(const float4*)(bias + c0);
    const float4 bv1 = *(const float4*)(bias + c0 + 4);
    float ps[8] = {0.f,0.f,0.f,0.f,0.f,0.f,0.f,0.f};
    float qs[8] = {0.f,0.f,0.f,0.f,0.f,0.f,0.f,0.f};
    for (int nb = wv * 4; nb < NN; nb += NWAVE * 4) {
        const int n = nb + g;
        if (n < NN) {
            const int o0 = offs[n];
            const int o1 = offs[n + 1];
            const int deg = o1 - o0;
            float a[8] = {0.f,0.f,0.f,0.f,0.f,0.f,0.f,0.f};
            int j = o0;
            for (; j + 1 < o1; j += 2) {
                const int s0 = csr[j];
                const int s1 = csr[j + 1];
                const uint4 q0 = *(const uint4*)(tl + (size_t)s0 * 128 + c0);
                const uint4 q1 = *(const uint4*)(tl + (size_t)s1 * 128 + c0);
                a[0] += b2f_lo(q0.x); a[1] += b2f_hi(q0.x);
                a[2] += b2f_lo(q0.y); a[3] += b2f_hi(q0.y);
                a[4] += b2f_lo(q0.z); a[5] += b2f_hi(q0.z);
                a[6] += b2f_lo(q0.w); a[7] += b2f_hi(q0.w);
                a[0] += b2f_lo(q1.x); a[1] += b2f_hi(q1.x);
                a[2] += b2f_lo(q1.y); a[3] += b2f_hi(q1.y);
                a[4] += b2f_lo(q1.z); a[5] += b2f_hi(q1.z);
                a[6] += b2f_lo(q1.w); a[7] += b2f_hi(q1.w);
            }
            if (j < o1) {
                const int s0 = csr[j];
                const uint4 q0 = *(const uint4*)(tl + (size_t)s0 * 128 + c0);
                a[0] += b2f_lo(q0.x); a[1] += b2f_hi(q0.x);
                a[2] += b2f_lo(q0.y); a[3] += b2f_hi(q0.y);
                a[4] += b2f_lo(q0.z); a[5] += b2f_hi(q0.z);
                a[6] += b2f_lo(q0.w); a[7] += b2f_hi(q0.w);
            }
            const float inv = 1.f / fmaxf((float)deg, 1.f);
            float* tp = tr + (size_t)n * 128 + c0;
            float4 t0 = *(float4*)tp;
            float4 t1 = *(float4*)(tp + 4);
            float v[8];
            v[0] = t0.x + a[0] * inv + bv0.x; v[1] = t0.y + a[1] * inv + bv0.y;
            v[2] = t0.z + a[2] * inv + bv0.z; v[3] = t0.w + a[3] * inv + bv0.w;
            v[4] = t1.x + a[4] * inv + bv1.x; v[5] = t1.y + a[5] * inv + bv1.y;
            v[6] = t1.z + a[6] * inv + bv1.z; v[7] = t1.w + a[7] * inv + bv1.w;
            *(float4*)tp       = make_float4(v[0], v[1], v[2], v[3]);
            *(float4*)(tp + 4) = make_float4(v[4], v[5], v[6], v[7]);
            #pragma unroll
            for (int i = 0; i < 8; ++i) { ps[i] += v[i]; qs[i] += v[i] * v[i]; }
        }
    }
    #pragma unroll
    for (int i = 0; i < 8; ++i) {
        ps[i] += __shfl_xor(ps[i], 16); ps[i] += __shfl_xor(ps[i], 32);
        qs[i] += __shfl_xor(qs[i], 16); qs[i] += __shfl_xor(qs[i], 32);
    }
    if (l < 16) {
        #pragma unroll
        for (int i = 0; i < 8; ++i) {
            red[wid][c0 + i]       = ps[i];
            red[wid][128 + c0 + i] = qs[i];
        }
    }
    __syncthreads();
    const int tc = threadIdx.x;
    const float s = red[0][tc] + red[1][tc] + red[2][tc] + red[3][tc];
    P[(size_t)blockIdx.x * 256 + tc] = s;
}

// ---------------------------------------------------------------------------
// GAT aggregation: 4 nodes/wave, 8 ch/lane, unroll-2 edge loop.
// ---------------------------------------------------------------------------
__global__ __launch_bounds__(256)
void k_attn_agg(const unsigned short* __restrict__ h1, const float* __restrict__ asrc,
                const float* __restrict__ adst, const int* __restrict__ offs,
                const int* __restrict__ csr, unsigned short* __restrict__ agg)
{
    const int l  = threadIdx.x & 63;
    const int g  = l >> 4;
    const int c0 = (l & 15) * 8;
    const int wv = blockIdx.x * 4 + (threadIdx.x >> 6);
    for (int nb = wv * 4; nb < NN; nb += NWAVE * 4) {
        const int n = nb + g;
        if (n >= NN) continue;
        const int o0 = offs[n];
        const int deg = offs[n + 1] - o0;
        const int total = deg + 1;                  // + self loop
        const float4 adv = *(const float4*)(adst + n * 4);
        float den0 = 0.f, den1 = 0.f, den2 = 0.f, den3 = 0.f;
        float acc[4][8];
        #pragma unroll
        for (int h = 0; h < 4; ++h)
            #pragma unroll
            for (int i = 0; i < 8; ++i) acc[h][i] = 0.f;
        int j = 0;
        for (; j + 1 < total; j += 2) {
            const int sidA = (j < deg) ? csr[o0 + j] : n;
            const int sidB = (j + 1 < deg) ? csr[o0 + j + 1] : n;
            const float4 avA = *(const float4*)(asrc + sidA * 4);
            const float4 avB = *(const float4*)(asrc + sidB * 4);
            const uint4 qA = *(const uint4*)(h1 + (size_t)sidA * 128 + c0);
            const uint4 qB = *(const uint4*)(h1 + (size_t)sidB * 128 + c0);
            float eA0 = avA.x + adv.x, eA1 = avA.y + adv.y;
            float eA2 = avA.z + adv.z, eA3 = avA.w + adv.w;
            eA0 = fmaxf(eA0, 0.2f * eA0); eA1 = fmaxf(eA1, 0.2f * eA1);
            eA2 = fmaxf(eA2, 0.2f * eA2); eA3 = fmaxf(eA3, 0.2f * eA3);
            const float wA0 = __expf(eA0), wA1 = __expf(eA1);
            const float wA2 = __expf(eA2), wA3 = __expf(eA3);
            float eB0 = avB.x + adv.x, eB1 = avB.y + adv.y;
            float eB2 = avB.z + adv.z, eB3 = avB.w + adv.w;
            eB0 = fmaxf(eB0, 0.2f * eB0); eB1 = fmaxf(eB1, 0.2f * eB1);
            eB2 = fmaxf(eB2, 0.2f * eB2); eB3 = fmaxf(eB3, 0.2f * eB3);
            const float wB0 = __expf(eB0), wB1 = __expf(eB1);
            const float wB2 = __expf(eB2), wB3 = __expf(eB3);
            den0 += wA0 + wB0; den1 += wA1 + wB1;
            den2 += wA2 + wB2; den3 += wA3 + wB3;
            float vA[8], vB[8];
            vA[0] = b2f_lo(qA.x); vA[1] = b2f_hi(qA.x);
            vA[2] = b2f_lo(qA.y); vA[3] = b2f_hi(qA.y);
            vA[4] = b2f_lo(qA.z); vA[5] = b2f_hi(qA.z);
            vA[6] = b2f_lo(qA.w); vA[7] = b2f_hi(qA.w);
            vB[0] = b2f_lo(qB.x); vB[1] = b2f_hi(qB.x);
            vB[2] = b2f_lo(qB.y); vB[3] = b2f_hi(qB.y);
            vB[4] = b2f_lo(qB.z); vB[5] = b2f_hi(qB.z);
            vB[6] = b2f_lo(qB.w); vB[7] = b2f_hi(qB.w);
            #pragma unroll
            for (int i = 0; i < 8; ++i) {
                acc[0][i] += wA0 * vA[i] + wB0 * vB[i];
                acc[1][i] += wA1 * vA[i] + wB1 * vB[i];
                acc[2][i] += wA2 * vA[i] + wB2 * vB[i];
                acc[3][i] += wA3 * vA[i] + wB3 * vB[i];
            }
        }
        if (j < total) {
            const int sid = (j < deg) ? csr[o0 + j] : n;
            const float4 av = *(const float4*)(asrc + sid * 4);
            const uint4 q = *(const uint4*)(h1 + (size_t)sid * 128 + c0);
            float e0 = av.x + adv.x, e1 = av.y + adv.y;
            float e2 = av.z + adv.z, e3 = av.w + adv.w;
            e0 = fmaxf(e0, 0.2f * e0); e1 = fmaxf(e1, 0.2f * e1);
            e2 = fmaxf(e2, 0.2f * e2); e3 = fmaxf(e3, 0.2f * e3);
            const float w0 = __expf(e0), w1 = __expf(e1);
            const float w2 = __expf(e2), w3 = __expf(e3);
            den0 += w0; den1 += w1; den2 += w2; den3 += w3;
            float v[8];
            v[0] = b2f_lo(q.x); v[1] = b2f_hi(q.x);
            v[2] = b2f_lo(q.y); v[3] = b2f_hi(q.y);
            v[4] = b2f_lo(q.z); v[5] = b2f_hi(q.z);
            v[6] = b2f_lo(q.w); v[7] = b2f_hi(q.w);
            #pragma unroll
            for (int i = 0; i < 8; ++i) {
                acc[0][i] += w0 * v[i];
                acc[1][i] += w1 * v[i];
                acc[2][i] += w2 * v[i];
                acc[3][i] += w3 * v[i];
            }
        }
        const float r[4] = {1.f / den0, 1.f / den1, 1.f / den2, 1.f / den3};
        #pragma unroll
        for (int h = 0; h < 4; ++h) {
            uint4 ov;
            ov.x = pack2(acc[h][0] * r[h], acc[h][1] * r[h]);
            ov.y = pack2(acc[h][2] * r[h], acc[h][3] * r[h]);
            ov.z = pack2(acc[h][4] * r[h], acc[h][5] * r[h]);
            ov.w = pack2(acc[h][6] * r[h], acc[h][7] * r[h]);
            *(uint4*)(agg + (size_t)n * 512 + h * 128 + c0) = ov;
        }
    }
}

// ---------------------------------------------------------------------------
// BN stats phase A: per-block partials, NO atomics.
// ---------------------------------------------------------------------------
__global__ __launch_bounds__(256)
void k_statsA_b2(const unsigned short* __restrict__ X, float* __restrict__ P)
{
    const int c = threadIdx.x * 2;
    const int b = blockIdx.x;
    const int r0 = b * 64;
    const int r1 = min(r0 + 64, NN);
    float s0 = 0.f, s1 = 0.f, q0 = 0.f, q1 = 0.f;
    for (int r = r0; r < r1; ++r) {
        const uint32_t u = *(const uint32_t*)(X + (size_t)r * 512 + c);
        const float v0 = b2f_lo(u), v1 = b2f_hi(u);
        s0 += v0; q0 += v0 * v0;
        s1 += v1; q1 += v1 * v1;
    }
    *(float2*)(P + (size_t)b * 1024 + c) = make_float2(s0, s1);
    *(float2*)(P + (size_t)b * 1024 + 512 + c) = make_float2(q0, q1);
}

__global__ __launch_bounds__(64)
void k_statsA_f(const float* __restrict__ X, float* __restrict__ P)
{
    const int c = threadIdx.x;
    const int b = blockIdx.x;
    const int r0 = b * 64;
    const int r1 = min(r0 + 64, NN);
    float s = 0.f, q = 0.f;
    for (int r = r0; r < r1; ++r) {
        const float v = X[(size_t)r * 64 + c];
        s += v; q += v * v;
    }
    P[(size_t)b * 128 + c] = s;
    P[(size_t)b * 128 + 64 + c] = q;
}

// ---------------------------------------------------------------------------
// Stage-1 tree reduce: P2[g] = sum of rows {g, g+G2, ...} of P (nb x C2).
// ---------------------------------------------------------------------------
__global__ __launch_bounds__(256)
void k_red1(const float* __restrict__ P, float* __restrict__ P2, int C2, int nb)
{
    const int g = blockIdx.x;
    for (int c = threadIdx.x; c < C2; c += 256) {
        float s = 0.f;
        for (int b = g; b < nb; b += G2) s += P[(size_t)b * C2 + c];
        P2[(size_t)g * C2 + c] = s;
    }
}

// ---------------------------------------------------------------------------
// BN stats phase B + final: reduce nb partials, emit scale/shift.
// ---------------------------------------------------------------------------
template<int CHUNK>
__global__ void k_bn_reduce(const float* __restrict__ P, int C, int nb,
                            const float* __restrict__ g, const float* __restrict__ be,
                            float* __restrict__ scale, float* __restrict__ shift)
{
    __shared__ float sb[8 * CHUNK];
    __shared__ float qb[8 * CHUNK];
    const int t = threadIdx.x;
    const int cl = t & (CHUNK - 1);
    const int grp = t / CHUNK;
    const int c = blockIdx.x * CHUNK + cl;
    float s = 0.f, q = 0.f;
    for (int b = grp; b < nb; b += 8) {
        s += P[(size_t)b * 2 * C + c];
        q += P[(size_t)b * 2 * C + C + c];
    }
    sb[grp * CHUNK + cl] = s;
    qb[grp * CHUNK + cl] = q;
    __syncthreads();
    if (t < CHUNK) {
        float S = 0.f, Q = 0.f;
        #pragma unroll
        for (int g2 = 0; g2 < 8; ++g2) { S += sb[g2 * CHUNK + t]; Q += qb[g2 * CHUNK + t]; }
        const int cc = blockIdx.x * CHUNK + t;
        const float mean = S / (float)NN;
        float var = Q / (float)NN - mean * mean;
        var = fmaxf(var, 0.f);
        const float sc = g[cc] * rsqrtf(var + BN_EPS);
        scale[cc] = sc;
        shift[cc] = be[cc] - mean * sc;
    }
}

// ---------------------------------------------------------------------------
__global__ void k_bn_elu_f2b(const float* __restrict__ X, unsigned short* __restrict__ D,
                             const float* __restrict__ scale, const float* __restrict__ shift,
                             int Cm1, int total)
{
    const int i = (blockIdx.x * 256 + threadIdx.x) * 4;
    if (i >= total) return;
    const int c = i & Cm1;
    const float4 x = *(const float4*)(X + i);
    float o[4] = {x.x, x.y, x.z, x.w};
    #pragma unroll
    for (int k = 0; k < 4; ++k) {
        const float v = o[k] * scale[c + k] + shift[c + k];
        o[k] = (v > 0.f) ? v : (__expf(v) - 1.f);
    }
    uint2 ov;
    ov.x = pack2(o[0], o[1]); ov.y = pack2(o[2], o[3]);
    *(uint2*)(D + i) = ov;
}

__global__ void k_bn_elu_b2b(unsigned short* __restrict__ X,
                             const float* __restrict__ scale, const float* __restrict__ shift,
                             int Cm1, int total)
{
    const int i = (blockIdx.x * 256 + threadIdx.x) * 4;
    if (i >= total) return;
    const int c = i & Cm1;
    const uint2 u = *(const uint2*)(X + i);
    float o[4] = {b2f_lo(u.x), b2f_hi(u.x), b2f_lo(u.y), b2f_hi(u.y)};
    #pragma unroll
    for (int k = 0; k < 4; ++k) {
        const float v = o[k] * scale[c + k] + shift[c + k];
        o[k] = (v > 0.f) ? v : (__expf(v) - 1.f);
    }
    uint2 ov;
    ov.x = pack2(o[0], o[1]); ov.y = pack2(o[2], o[3]);
    *(uint2*)(X + i) = ov;
}

// ---------------------------------------------------------------------------
// Fused layer-1 BN+ELU -> h1b (bf16) + GAT coefficients (one wave per node)
// ---------------------------------------------------------------------------
__global__ __launch_bounds__(256)
void k_bn_elu_coef(const float* __restrict__ X, unsigned short* __restrict__ D,
                   const float* __restrict__ scale, const float* __restrict__ shift,
                   const float* __restrict__ ats, const float* __restrict__ atd,
                   float* __restrict__ asrc, float* __restrict__ adst)
{
    const int l = threadIdx.x & 63;
    const int wv = blockIdx.x * 4 + (threadIdx.x >> 6);
    const int c = l * 2;
    const float2 sc = *(const float2*)(scale + c);
    const float2 sh = *(const float2*)(shift + c);
    float2 sa[4], da[4];
    #pragma unroll
    for (int h = 0; h < 4; ++h) {
        sa[h] = *(const float2*)(ats + h * 128 + c);
        da[h] = *(const float2*)(atd + h * 128 + c);
    }
    for (int n = wv; n < NN; n += NWAVE) {
        const float2 xv = *(const float2*)(X + (size_t)n * 128 + c);
        float v0 = xv.x * sc.x + sh.x;
        float v1 = xv.y * sc.y + sh.y;
        v0 = (v0 > 0.f) ? v0 : (__expf(v0) - 1.f);
        v1 = (v1 > 0.f) ? v1 : (__expf(v1) - 1.f);
        const uint32_t p = pack2(v0, v1);
        *(uint32_t*)(D + (size_t)n * 128 + c) = p;
        const float r0 = b2f_lo(p), r1 = b2f_hi(p);   // use bf16-rounded values
        float ps[4], pd[4];
        #pragma unroll
        for (int h = 0; h < 4; ++h) {
            ps[h] = r0 * sa[h].x + r1 * sa[h].y;
            pd[h] = r0 * da[h].x + r1 * da[h].y;
        }
        #pragma unroll
        for (int o = 1; o < 64; o <<= 1) {
            #pragma unroll
            for (int h = 0; h < 4; ++h) {
                ps[h] += __shfl_xor(ps[h], o);
                pd[h] += __shfl_xor(pd[h], o);
            }
        }
        if (l == 0) {
            *(float4*)(asrc + n * 4) = make_float4(ps[0], ps[1], ps[2], ps[3]);
            *(float4*)(adst + n * 4) = make_float4(pd[0], pd[1], pd[2], pd[3]);
        }
    }
}

// ---------------------------------------------------------------------------
// Fused layer-4 BN+ELU + final linear (grid-stride, one wave per node)
// ---------------------------------------------------------------------------
__global__ __launch_bounds__(256)
void k_bn_elu_fc2(const float* __restrict__ X, const float* __restrict__ scale,
                  const float* __restrict__ shift, const float* __restrict__ W,
                  const float* __restrict__ bias, float* __restrict__ out)
{
    const int c = threadIdx.x & 63;
    const int gw = blockIdx.x * 4 + (threadIdx.x >> 6);
    const float sc = scale[c], sh = shift[c];
    const float w0 = W[c], w1 = W[64 + c];
    const float b0 = bias[0], b1 = bias[1];
    for (int n = gw; n < NN; n += NWAVE) {
        float v = X[(size_t)n * 64 + c] * sc + sh;
        v = (v > 0.f) ? v : (__expf(v) - 1.f);
        float p0 = v * w0;
        float p1 = v * w1;
        #pragma unroll
        for (int o = 1; o < 64; o <<= 1) {
            p0 += __shfl_xor(p0, o);
            p1 += __shfl_xor(p1, o);
        }
        if (c == 0) {
            out[n * 2 + 0] = p0 + b0;
            out[n * 2 + 1] = p1 + b1;
        }
    }
}

// ---------------------------------------------------------------------------
extern "C" void kernel_launch(void* const* d_in, const int* in_sizes, int n_in,
                              void* d_out, int out_size, void* d_ws, size_t ws_size,
                              hipStream_t stream)
{
    const float* x     = (const float*)d_in[0];
    const int*   ei    = (const int*)d_in[1];
    const float* W1l   = (const float*)d_in[2];
    const float* b1    = (const float*)d_in[3];
    const float* W1r   = (const float*)d_in[4];
    const float* g1    = (const float*)d_in[5];
    const float* be1   = (const float*)d_in[6];
    const float* Wg    = (const float*)d_in[7];
    const float* a_s   = (const float*)d_in[8];
    const float* a_d   = (const float*)d_in[9];
    const float* gbias = (const float*)d_in[10];
    const float* g2    = (const float*)d_in[11];
    const float* be2   = (const float*)d_in[12];
    const float* W2l   = (const float*)d_in[13];
    const float* b2    = (const float*)d_in[14];
    const float* W2r   = (const float*)d_in[15];
    const float* g3    = (const float*)d_in[16];
    const float* be3   = (const float*)d_in[17];
    const float* Wf1   = (const float*)d_in[18];
    const float* bf1   = (const float*)d_in[19];
    const float* g4    = (const float*)d_in[20];
    const float* be4   = (const float*)d_in[21];
    const float* Wf2   = (const float*)d_in[22];
    const float* bf2   = (const float*)d_in[23];
    const int* src = ei;
    const int* dst = ei + EE;

    char* ws = (char*)d_ws;
    size_t off = 0;
    auto alloc = [&](size_t bytes) -> char* {
        char* p = ws + off;
        off += (bytes + 255) & ~(size_t)255;
        return p;
    };
    unsigned short* xb   = (unsigned short*)alloc((size_t)NN * 256 * 2);
    unsigned short* waren= (unsigned short*)alloc(270336 * 2);
    unsigned short* tlb  = (unsigned short*)alloc((size_t)NN * 128 * 2);
    float*          trF  = (float*)alloc((size_t)NN * 128 * 4);
    unsigned short* h1b  = (unsigned short*)alloc((size_t)NN * 128 * 2);
    unsigned short* aggb = (unsigned short*)alloc((size_t)NN * 512 * 2);
    unsigned short* gatb = (unsigned short*)alloc((size_t)NN * 512 * 2);
    float* asrc  = (float*)alloc((size_t)NN * 4 * 4);
    float* adst  = (float*)alloc((size_t)NN * 4 * 4);
    float* ats   = (float*)alloc(512 * 4);
    float* atd   = (float*)alloc(512 * 4);
    float* pstat = (float*)alloc((size_t)GB * 1024 * 4);    // 3.2 MB (max user)
    float* pstat2= (float*)alloc((size_t)G2 * 1024 * 4);    // 256 KB stage-1 out
    float* scsh  = (float*)alloc(1024 * 4);
    int*   cntfill = (int*)alloc((size_t)NN * 2 * 4);
    int*   offs  = (int*)alloc((size_t)(NN + 1) * 4);
    int*   csr   = (int*)alloc((size_t)EE * 4);
    int*   bsum  = (int*)alloc((size_t)NB_SCAN * 4);
    if (off > ws_size) return;
    (void)in_sizes; (void)n_in; (void)out_size;

    unsigned short* W1cat = waren;            // W1l || W1r : 256 rows x 256
    unsigned short* Wg_b  = waren + 65536;    // 512 x 128
    unsigned short* W2cat = waren + 131072;   // W2l || W2r : 256 rows x 512
    unsigned short* Wf1_b = waren + 262144;   // 64 x 128

    int* cnt  = cntfill;
    int* fill = cntfill + NN;
    float* scale = scsh;
    float* shift = scsh + 512;

    // ---- prep (converts + attention projection) + CSR build ----
    k_prep<<<7310, 256, 0, stream>>>(x, xb, W1l, W1r, Wg, W2l, W2r, Wf1, waren,
                                     a_s, a_d, ats, atd);
    hipMemsetAsync(cntfill, 0, (size_t)NN * 2 * 4, stream);
    k_count<<<(EE + 255) / 256, 256, 0, stream>>>(dst, cnt);
    k_scan_blk<<<NB_SCAN, 256, 0, stream>>>(cnt, offs, bsum, NN);
    k_scan_top<<<1, 256, 0, stream>>>(bsum, offs, NN);
    k_scan_add<<<NB_SCAN, 256, 0, stream>>>(offs, bsum, NN);
    k_fill<<<(EE + 255) / 256, 256, 0, stream>>>(src, dst, offs, fill, csr);

    const int gy = (NN + 127) / 128;   // 391

    // ---- Layer 1: SAGE(256 -> 128) + BN + ELU (+coef fused) ----
    gemm_w256<<<gy, 256, 0, stream>>>(xb, W1cat, tlb, trF, NN, 256);
    k_sage_agg<<<GAGG, 256, 0, stream>>>(tlb, trF, b1, offs, csr, pstat);
    k_red1<<<G2, 256, 0, stream>>>(pstat, pstat2, 256, GAGG);
    k_bn_reduce<128><<<1, 1024, 0, stream>>>(pstat2, 128, G2, g1, be1, scale, shift);
    k_bn_elu_coef<<<2048, 256, 0, stream>>>(trF, h1b, scale, shift, ats, atd, asrc, adst);

    // ---- Layer 2: GAT(128 -> 4x128) + BN + ELU ----
    k_attn_agg<<<2048, 256, 0, stream>>>(h1b, asrc, adst, offs, csr, aggb);
    gemm_heads<<<dim3(gy, 4), 256, 0, stream>>>(aggb, Wg_b, gbias, gatb);
    k_statsA_b2<<<GB, 256, 0, stream>>>(gatb, pstat);
    k_red1<<<G2, 256, 0, stream>>>(pstat, pstat2, 1024, GB);
    k_bn_reduce<128><<<4, 1024, 0, stream>>>(pstat2, 512, G2, g2, be2, scale, shift);
    k_bn_elu_b2b<<<(NN * 512 / 4 + 255) / 256, 256, 0, stream>>>(gatb, scale, shift, 511, NN * 512);

    // ---- Layer 3: SAGE(512 -> 128) + BN + ELU ----
    gemm_w256<<<gy, 256, 0, stream>>>(gatb, W2cat, tlb, trF, NN, 512);
    k_sage_agg<<<GAGG, 256, 0, stream>>>(tlb, trF, b2, offs, csr, pstat);
    k_red1<<<G2, 256, 0, stream>>>(pstat, pstat2, 256, GAGG);
    k_bn_reduce<128><<<1, 1024, 0, stream>>>(pstat2, 128, G2, g3, be3, scale, shift);
    k_bn_elu_f2b<<<(NN * 128 / 4 + 255) / 256, 256, 0, stream>>>(trF, h1b, scale, shift, 127, NN * 128);

    // ---- Layer 4: Linear(128 -> 64) + BN ----
    gemm_bf16mm<<<dim3(1, gy), 256, 0, stream>>>(h1b, Wf1_b, bf1, nullptr, trF,
                                                 0, NN, 128, 64, 0, 64);
    k_statsA_f<<<GB, 64, 0, stream>>>(trF, pstat);
    k_red1<<<G2, 256, 0, stream>>>(pstat, pstat2, 128, GB);
    k_bn_reduce<64><<<1, 512, 0, stream>>>(pstat2, 64, G2, g4, be4, scale, shift);

    // ---- Layer 4 ELU + Layer 5 Linear(64 -> 2), fused ----
    k_bn_elu_fc2<<<2048, 256, 0, stream>>>(trF, scale, shift, Wf2, bf2, (float*)d_out);
}